// Round 5
// baseline (155.452 us; speedup 1.0000x reference)
//
#include <hip/hip_runtime.h>
#include <hip/hip_bf16.h>

#define Bsz 4
#define Lsz 2048
#define Hsz 8

typedef __attribute__((ext_vector_type(8)))  short bf16x8;
typedef __attribute__((ext_vector_type(4)))  short bf16x4;
typedef __attribute__((ext_vector_type(4)))  float f32x4;

__device__ __forceinline__ short f2bs(float f) {   // RNE
    union { float f; unsigned u; } v; v.f = f;
    unsigned r = v.u + 0x7FFFu + ((v.u >> 16) & 1u);
    return (short)(r >> 16);
}
__device__ __forceinline__ short f2bs_rh(float f) { // round-half-up, 2 ops
    return (short)((__float_as_uint(f) + 0x8000u) >> 16);
}

// async global->LDS, 16B per lane; LDS dest is wave-uniform base + lane*16
__device__ __forceinline__ void stage16(const short* g, short* l) {
    __builtin_amdgcn_global_load_lds(
        (const __attribute__((address_space(1))) unsigned int*)g,
        (__attribute__((address_space(3))) unsigned int*)l,
        16, 0, 0);
}

// ---------------- pre-pass: K, V -> bf16 fragments (kq-major) ----------------
// Per (bh, 64-key tile), 8 chunks x 1 KB each, kq = key-16-block owner wave:
// K chunk c = kq*2+eb:   lane(ln,quad): K[kq*16+ln][eb*32+quad*8+j]   (A 16x16x32)
// V chunk c = kq*2+dgp:  lane 16B = [frag(dg=2dgp) | frag(dg=2dgp+1)], each
//    frag 8B = V[kq*16+quad*4+j][dg*16+ln], j=0..3                    (A 16x16x16)
__global__ __launch_bounds__(256) void prep_kv(
    const float* __restrict__ ksrc, const float* __restrict__ vsrc,
    short* __restrict__ Kf, short* __restrict__ Vf)
{
    __shared__ float Tl[64][65];
    const int raw = blockIdx.x;
    const int tid = threadIdx.x;
    const bool isK = raw < Bsz*Hsz*32;
    const int bid = isK ? raw : raw - Bsz*Hsz*32;
    const int tl = bid & 31, bh = bid >> 5;
    const int b = bh >> 3, h = bh & 7;

    const int row = tid >> 2, c0 = (tid & 3) * 16;
    const float* src = (isK ? ksrc : vsrc)
                     + (((size_t)b*Lsz + tl*64 + row)*Hsz + h)*64 + c0;
    *(float4*)&Tl[row][c0]      = *(const float4*)(src);
    *(float4*)&Tl[row][c0 + 4]  = *(const float4*)(src + 4);
    *(float4*)&Tl[row][c0 + 8]  = *(const float4*)(src + 8);
    *(float4*)&Tl[row][c0 + 12] = *(const float4*)(src + 12);
    __syncthreads();

    const int lane = tid & 63, ln = lane & 15, quad = lane >> 4;
    if (isK) {
        short* dst = Kf + (size_t)bid * 4096;
        #pragma unroll
        for (int cc = 0; cc < 2; ++cc) {
            const int c  = (tid >> 6)*2 + cc;      // 0..7 = kq*2+eb
            const int kq = c >> 1, eb = c & 1;
            const float* rp = &Tl[kq*16 + ln][eb*32 + quad*8];
            bf16x8 o = {f2bs(rp[0]),f2bs(rp[1]),f2bs(rp[2]),f2bs(rp[3]),
                        f2bs(rp[4]),f2bs(rp[5]),f2bs(rp[6]),f2bs(rp[7])};
            *(bf16x8*)(dst + c*512 + lane*8) = o;
        }
    } else {
        short* dst = Vf + (size_t)bid * 4096;
        #pragma unroll
        for (int cc = 0; cc < 2; ++cc) {
            const int c   = (tid >> 6)*2 + cc;     // 0..7 = kq*2+dgp
            const int kq  = c >> 1, dgp = c & 1;
            const int s0  = kq*16 + quad*4;
            const int d0  = dgp*32 + ln;           // dg=2dgp
            const int d1  = dgp*32 + 16 + ln;      // dg=2dgp+1
            bf16x8 o = {f2bs(Tl[s0+0][d0]), f2bs(Tl[s0+1][d0]),
                        f2bs(Tl[s0+2][d0]), f2bs(Tl[s0+3][d0]),
                        f2bs(Tl[s0+0][d1]), f2bs(Tl[s0+1][d1]),
                        f2bs(Tl[s0+2][d1]), f2bs(Tl[s0+3][d1])};
            *(bf16x8*)(dst + c*512 + lane*8) = o;
        }
    }
}

// ---------------- main: barrier-free, truly drain-free wave pipelines ----------
// 256 thr = 4 waves; wave kq owns keys kq*16..+16 of every tile x ALL 64 queries.
// The ONLY vmcnt ops in the loop are the 4 stage16/tile -> counted waits work:
// steady state WAITN(6) before K reads, WAITN(4) before V reads; tile t+1's
// loads stay in flight across the whole body. Q in REGISTERS (32 VGPR);
// c2*delta in LDS (ds_read, lgkmcnt - not vmcnt). No __syncthreads in the loop.
// 40 KB LDS -> 4 blocks/CU = 16 waves/CU.
__global__ __launch_bounds__(256, 4) void dsattn_main(
    const float* __restrict__ q,
    const short* __restrict__ Kf,
    const short* __restrict__ Vf,
    const float* __restrict__ tau,
    const float* __restrict__ delta,
    float* __restrict__ out)
{
    __shared__ __align__(16) short Kb[2][4096];   // 16 KB dbuf (4 x 2KB wave slices)
    __shared__ __align__(16) short Vb[2][4096];   // 16 KB dbuf
    __shared__ float dls[Lsz];                    //  8 KB c2*delta[b][:]
    // total 40 KB -> 4 blocks/CU

    const int tid  = threadIdx.x;
    const int kq   = tid >> 6;        // wave id == key-quarter
    const int lane = tid & 63;
    const int ln   = lane & 15;
    const int quad = lane >> 4;

    const int bh = blockIdx.x;
    const int b  = bh >> 3, h = bh & 7;
    // co-resident {y,y+8,y+16,y+24} -> qt {31-2a, 2a, 30-2a, 2a+1}: 66 tiles/CU
    const int y = blockIdx.y, g8 = y >> 3, a = y & 7;
    const int qt = (g8 == 0) ? 31 - 2*a : (g8 == 1) ? 2*a
                 : (g8 == 2) ? 30 - 2*a : 2*a + 1;
    const int q0 = qt * 64;
    const int T  = qt + 1;            // 64-key tiles

    const float c2  = 0.125f * 1.44269504f;   // scale * log2(e)
    const float st2 = c2 * tau[b];

    // per-wave incremental staging pointers (tile stride = 4096 shorts = 8 KB)
    const short* gK = Kf + (size_t)bh*(32*4096) + kq*1024 + lane*8;
    const short* gV = Vf + (size_t)bh*(32*4096) + kq*1024 + lane*8;

    // wave's private LDS slices
    short* const myK0 = &Kb[0][kq*1024];
    short* const myV0 = &Vb[0][kq*1024];

    // exactly 4 vmcnt ops per tile - nothing else in the loop touches vmcnt
#define STAGE(buf) do {                                                     \
        short* k_ = (buf) ? myK0 + 4096 : myK0;                             \
        short* v_ = (buf) ? myV0 + 4096 : myV0;                             \
        stage16(gK + 0*512, k_ + 0*512);                                    \
        stage16(gK + 1*512, k_ + 1*512);                                    \
        stage16(gV + 0*512, v_ + 0*512);                                    \
        stage16(gV + 1*512, v_ + 1*512);                                    \
        gK += 4096; gV += 4096;                                             \
        __builtin_amdgcn_sched_barrier(0);                                  \
    } while (0)
#define WAITN(n) do {                                                       \
        asm volatile("s_waitcnt vmcnt(" #n ")" ::: "memory");               \
        __builtin_amdgcn_sched_barrier(0);                                  \
    } while (0)

    STAGE(0);                         // tile 0 in flight first

    // stage c2*delta (256 thr x 8 floats) - prologue only
    {
        const float* dsrc = delta + (size_t)b*Lsz + tid*8;
        float4 av = *(const float4*)(dsrc);
        float4 cv = *(const float4*)(dsrc + 4);
        av.x*=c2; av.y*=c2; av.z*=c2; av.w*=c2;
        cv.x*=c2; cv.y*=c2; cv.z*=c2; cv.w*=c2;
        *(float4*)&dls[tid*8]     = av;
        *(float4*)&dls[tid*8 + 4] = cv;
    }

    // Q fragments in registers (all 64 queries; B-operand of 16x16x32)
    bf16x8 qf[4][2];
    #pragma unroll
    for (int qg = 0; qg < 4; ++qg) {
        const float* qrow = q + (((size_t)b*Lsz + q0 + qg*16 + ln)*Hsz + h)*64;
        float4 a0 = *(const float4*)(qrow + quad*8);
        float4 a1 = *(const float4*)(qrow + quad*8 + 4);
        float4 b0 = *(const float4*)(qrow + 32 + quad*8);
        float4 b1 = *(const float4*)(qrow + 32 + quad*8 + 4);
        qf[qg][0] = (bf16x8){f2bs(a0.x),f2bs(a0.y),f2bs(a0.z),f2bs(a0.w),
                             f2bs(a1.x),f2bs(a1.y),f2bs(a1.z),f2bs(a1.w)};
        qf[qg][1] = (bf16x8){f2bs(b0.x),f2bs(b0.y),f2bs(b0.z),f2bs(b0.w),
                             f2bs(b1.x),f2bs(b1.y),f2bs(b1.z),f2bs(b1.w)};
    }

    f32x4 oacc[4][4];                 // [dg][qg]; O[q=qg*16+ln][d=dg*16+quad*4+i]
    #pragma unroll
    for (int dg = 0; dg < 4; ++dg)
        #pragma unroll
        for (int qg = 0; qg < 4; ++qg)
            oacc[dg][qg] = (f32x4){0.f,0.f,0.f,0.f};
    float l_acc[4] = {0.f,0.f,0.f,0.f};

    __syncthreads();                  // tile 0 + dls resident (single drain)

#define TILE_BODY(t_, MASKED, HASNEXT) do {                                 \
        const short* Kc_ = ((t_) & 1) ? myK0 + 4096 : myK0;                 \
        const short* Vc_ = ((t_) & 1) ? myV0 + 4096 : myV0;                 \
        if (HASNEXT) STAGE(((t_)+1) & 1);                                   \
        if (HASNEXT) WAITN(6); else WAITN(2);      /* K(t) resident */      \
        bf16x8 kf0_ = *(const bf16x8*)(Kc_ + 0*512 + lane*8);               \
        bf16x8 kf1_ = *(const bf16x8*)(Kc_ + 1*512 + lane*8);               \
        f32x4 sacc_[4];                                                     \
        __builtin_amdgcn_s_setprio(1);                                      \
        _Pragma("unroll")                                                   \
        for (int qg = 0; qg < 4; ++qg) {                                    \
            f32x4 z_ = (f32x4){0.f,0.f,0.f,0.f};                            \
            z_ = __builtin_amdgcn_mfma_f32_16x16x32_bf16(kf0_, qf[qg][0], z_, 0,0,0); \
            sacc_[qg] = __builtin_amdgcn_mfma_f32_16x16x32_bf16(kf1_, qf[qg][1], z_, 0,0,0); \
        }                                                                   \
        __builtin_amdgcn_s_setprio(0);                                      \
        if (MASKED) {                                                       \
            _Pragma("unroll")                                               \
            for (int qg = 0; qg < 4; ++qg)                                  \
                _Pragma("unroll")                                           \
                for (int r = 0; r < 4; ++r)                                 \
                    if (kq*16 + quad*4 + r > qg*16 + ln) sacc_[qg][r] = -1e30f; \
        }                                                                   \
        f32x4 dlv_ = *(const f32x4*)&dls[(t_)*64 + kq*16 + quad*4];         \
        bf16x4 pT_[4];                                                      \
        _Pragma("unroll")                                                   \
        for (int qg = 0; qg < 4; ++qg) {                                    \
            float p0_ = __builtin_amdgcn_exp2f(fmaf(sacc_[qg][0], st2, dlv_[0])); \
            float p1_ = __builtin_amdgcn_exp2f(fmaf(sacc_[qg][1], st2, dlv_[1])); \
            float p2_ = __builtin_amdgcn_exp2f(fmaf(sacc_[qg][2], st2, dlv_[2])); \
            float p3_ = __builtin_amdgcn_exp2f(fmaf(sacc_[qg][3], st2, dlv_[3])); \
            l_acc[qg] += (p0_ + p1_) + (p2_ + p3_);                         \
            pT_[qg] = (bf16x4){f2bs_rh(p0_), f2bs_rh(p1_),                  \
                               f2bs_rh(p2_), f2bs_rh(p3_)};                 \
        }                                                                   \
        if (HASNEXT) WAITN(4); else WAITN(0);      /* V(t) resident */      \
        bf16x8 vv0_ = *(const bf16x8*)(Vc_ + 0*512 + lane*8);               \
        bf16x8 vv1_ = *(const bf16x8*)(Vc_ + 1*512 + lane*8);               \
        bf16x4 vf_[4];                                                      \
        vf_[0] = (bf16x4){vv0_[0], vv0_[1], vv0_[2], vv0_[3]};              \
        vf_[1] = (bf16x4){vv0_[4], vv0_[5], vv0_[6], vv0_[7]};              \
        vf_[2] = (bf16x4){vv1_[0], vv1_[1], vv1_[2], vv1_[3]};              \
        vf_[3] = (bf16x4){vv1_[4], vv1_[5], vv1_[6], vv1_[7]};              \
        __builtin_amdgcn_s_setprio(1);                                      \
        _Pragma("unroll")                                                   \
        for (int dg = 0; dg < 4; ++dg)                                      \
            _Pragma("unroll")                                               \
            for (int qg = 0; qg < 4; ++qg)                                  \
                oacc[dg][qg] = __builtin_amdgcn_mfma_f32_16x16x16bf16_1k(   \
                    vf_[dg], pT_[qg], oacc[dg][qg], 0,0,0);                 \
        __builtin_amdgcn_s_setprio(0);                                      \
    } while (0)

    // barrier-free main loop; diagonal (masked) tile last, no staging
    for (int t = 0; t < T - 1; ++t) TILE_BODY(t, false, true);
    TILE_BODY(T - 1, true, false);

    // ---- epilogue: 4-way cross-kq reduction of O and l via LDS overlays ----
    float lq[4];
    #pragma unroll
    for (int qg = 0; qg < 4; ++qg) {
        float s = l_acc[qg];
        s += __shfl_xor(s, 16, 64);
        s += __shfl_xor(s, 32, 64);
        lq[qg] = s;                   // full-wave l for (qg, q=ln), replicated
    }
    float* KbF = (float*)&Kb[0][0];   // 8 KB wave-1 O, layout (dg*4+qg)*256+lane*4
    float* VbF = (float*)&Vb[0][0];   // 8 KB wave-3 O
    float* lred = dls;                // 256 f: [kq][qg][16 q]
    __syncthreads();                  // all loop reads of Kb/Vb/dls done

    if (lane < 16)
        #pragma unroll
        for (int qg = 0; qg < 4; ++qg) lred[kq*64 + qg*16 + ln] = lq[qg];
    if (kq == 1 || kq == 3) {
        float* dst = (kq == 1) ? KbF : VbF;
        #pragma unroll
        for (int dg = 0; dg < 4; ++dg)
            #pragma unroll
            for (int qg = 0; qg < 4; ++qg)
                *(f32x4*)(dst + (dg*4+qg)*256 + lane*4) = oacc[dg][qg];
    }
    __syncthreads();
    if (kq == 0 || kq == 2) {
        const float* srcp = (kq == 0) ? KbF : VbF;
        #pragma unroll
        for (int dg = 0; dg < 4; ++dg)
            #pragma unroll
            for (int qg = 0; qg < 4; ++qg) {
                f32x4 v = *(const f32x4*)(srcp + (dg*4+qg)*256 + lane*4);
                oacc[dg][qg][0] += v[0]; oacc[dg][qg][1] += v[1];
                oacc[dg][qg][2] += v[2]; oacc[dg][qg][3] += v[3];
            }
    }
    __syncthreads();
    if (kq == 2) {
        #pragma unroll
        for (int dg = 0; dg < 4; ++dg)
            #pragma unroll
            for (int qg = 0; qg < 4; ++qg)
                *(f32x4*)(KbF + (dg*4+qg)*256 + lane*4) = oacc[dg][qg];
    }
    __syncthreads();
    if (kq == 0) {
        float inv[4];
        #pragma unroll
        for (int qg = 0; qg < 4; ++qg)
            inv[qg] = 1.0f / (lred[qg*16 + ln] + lred[64 + qg*16 + ln]
                            + lred[128 + qg*16 + ln] + lred[192 + qg*16 + ln]);
        #pragma unroll
        for (int qg = 0; qg < 4; ++qg) {
            float* orow = out + (((size_t)b*Lsz + q0 + qg*16 + ln)*Hsz + h)*64;
            #pragma unroll
            for (int dg = 0; dg < 4; ++dg) {
                f32x4 v = *(const f32x4*)(KbF + (dg*4+qg)*256 + lane*4);
                float4 o = {(oacc[dg][qg][0] + v[0]) * inv[qg],
                            (oacc[dg][qg][1] + v[1]) * inv[qg],
                            (oacc[dg][qg][2] + v[2]) * inv[qg],
                            (oacc[dg][qg][3] + v[3]) * inv[qg]};
                *(float4*)(orow + dg*16 + quad*4) = o;
            }
        }
    }
#undef STAGE
#undef WAITN
#undef TILE_BODY
}

extern "C" void kernel_launch(void* const* d_in, const int* in_sizes, int n_in,
                              void* d_out, int out_size, void* d_ws, size_t ws_size,
                              hipStream_t stream) {
    (void)in_sizes; (void)n_in; (void)out_size; (void)ws_size;
    const float* q     = (const float*)d_in[0];
    const float* k     = (const float*)d_in[1];
    const float* v     = (const float*)d_in[2];
    const float* tau   = (const float*)d_in[3];
    const float* delta = (const float*)d_in[4];
    float* out = (float*)d_out;

    short* Kf = (short*)d_ws;                          // 8 MiB bf16 fragments
    short* Vf = (short*)d_ws + (size_t)(4*1024*1024);  // next 8 MiB

    prep_kv<<<dim3(Bsz*Hsz*32*2), dim3(256), 0, stream>>>(k, v, Kf, Vf);
    dsattn_main<<<dim3(Bsz*Hsz, 32), dim3(256), 0, stream>>>(q, Kf, Vf, tau, delta, out);
}

// Round 6
// 130.399 us; speedup vs baseline: 1.1921x; 1.1921x over previous
//
#include <hip/hip_runtime.h>
#include <hip/hip_bf16.h>

#define Bsz 4
#define Lsz 2048
#define Hsz 8

typedef __attribute__((ext_vector_type(8)))  short bf16x8;
typedef __attribute__((ext_vector_type(4)))  short bf16x4;
typedef __attribute__((ext_vector_type(4)))  float f32x4;

__device__ __forceinline__ short f2bs(float f) {   // RNE
    union { float f; unsigned u; } v; v.f = f;
    unsigned r = v.u + 0x7FFFu + ((v.u >> 16) & 1u);
    return (short)(r >> 16);
}
__device__ __forceinline__ short f2bs_rh(float f) { // round-half-up, 2 ops
    return (short)((__float_as_uint(f) + 0x8000u) >> 16);
}

// async global->LDS, 16B per lane; LDS dest is wave-uniform base + lane*16
__device__ __forceinline__ void stage16(const short* g, short* l) {
    __builtin_amdgcn_global_load_lds(
        (const __attribute__((address_space(1))) unsigned int*)g,
        (__attribute__((address_space(3))) unsigned int*)l,
        16, 0, 0);
}

// ---------------- pre-pass: K, V -> bf16 fragments (kq-major) ----------------
// Per (bh, 64-key tile), 8 chunks x 1 KB each, kq = key-16-block owner wave:
// K chunk c = kq*2+eb:   lane(ln,quad): K[kq*16+ln][eb*32+quad*8+j]   (A 16x16x32)
// V chunk c = kq*2+dgp:  lane 16B = [frag(dg=2dgp) | frag(dg=2dgp+1)], each
//    frag 8B = V[kq*16+quad*4+j][dg*16+ln], j=0..3                    (A 16x16x16)
__global__ __launch_bounds__(256) void prep_kv(
    const float* __restrict__ ksrc, const float* __restrict__ vsrc,
    short* __restrict__ Kf, short* __restrict__ Vf)
{
    __shared__ float Tl[64][65];
    const int raw = blockIdx.x;
    const int tid = threadIdx.x;
    const bool isK = raw < Bsz*Hsz*32;
    const int bid = isK ? raw : raw - Bsz*Hsz*32;
    const int tl = bid & 31, bh = bid >> 5;
    const int b = bh >> 3, h = bh & 7;

    const int row = tid >> 2, c0 = (tid & 3) * 16;
    const float* src = (isK ? ksrc : vsrc)
                     + (((size_t)b*Lsz + tl*64 + row)*Hsz + h)*64 + c0;
    *(float4*)&Tl[row][c0]      = *(const float4*)(src);
    *(float4*)&Tl[row][c0 + 4]  = *(const float4*)(src + 4);
    *(float4*)&Tl[row][c0 + 8]  = *(const float4*)(src + 8);
    *(float4*)&Tl[row][c0 + 12] = *(const float4*)(src + 12);
    __syncthreads();

    const int lane = tid & 63, ln = lane & 15, quad = lane >> 4;
    if (isK) {
        short* dst = Kf + (size_t)bid * 4096;
        #pragma unroll
        for (int cc = 0; cc < 2; ++cc) {
            const int c  = (tid >> 6)*2 + cc;      // 0..7 = kq*2+eb
            const int kq = c >> 1, eb = c & 1;
            const float* rp = &Tl[kq*16 + ln][eb*32 + quad*8];
            bf16x8 o = {f2bs(rp[0]),f2bs(rp[1]),f2bs(rp[2]),f2bs(rp[3]),
                        f2bs(rp[4]),f2bs(rp[5]),f2bs(rp[6]),f2bs(rp[7])};
            *(bf16x8*)(dst + c*512 + lane*8) = o;
        }
    } else {
        short* dst = Vf + (size_t)bid * 4096;
        #pragma unroll
        for (int cc = 0; cc < 2; ++cc) {
            const int c   = (tid >> 6)*2 + cc;     // 0..7 = kq*2+dgp
            const int kq  = c >> 1, dgp = c & 1;
            const int s0  = kq*16 + quad*4;
            const int d0  = dgp*32 + ln;           // dg=2dgp
            const int d1  = dgp*32 + 16 + ln;      // dg=2dgp+1
            bf16x8 o = {f2bs(Tl[s0+0][d0]), f2bs(Tl[s0+1][d0]),
                        f2bs(Tl[s0+2][d0]), f2bs(Tl[s0+3][d0]),
                        f2bs(Tl[s0+0][d1]), f2bs(Tl[s0+1][d1]),
                        f2bs(Tl[s0+2][d1]), f2bs(Tl[s0+3][d1])};
            *(bf16x8*)(dst + c*512 + lane*8) = o;
        }
    }
}

// ---------------- main: barrier-free, truly drain-free wave pipelines ----------
// 256 thr = 4 waves; wave kq owns keys kq*16..+16 of every tile x ALL 64 queries.
// The ONLY vmcnt ops in the loop are the 4 stage16/tile -> counted waits work:
// steady state WAITN(6) before K reads, WAITN(4) before V reads; tile t+1's
// loads stay in flight across the whole body. Q in REGISTERS (32 VGPR);
// c2*delta in LDS (ds_read, lgkmcnt - not vmcnt). No __syncthreads in the loop.
// launch_bounds(256,3): 170 unified regs/wave (Q32 + O64 + temps fit, NO SPILL
// - R5's (256,4)=128 cap spilled ~100 B/thread: WRITE_SIZE 16->41 MB).
// 40 KB LDS; occupancy = 3 blocks/CU (VGPR-limited), 12 waves/CU.
__global__ __launch_bounds__(256, 3) void dsattn_main(
    const float* __restrict__ q,
    const short* __restrict__ Kf,
    const short* __restrict__ Vf,
    const float* __restrict__ tau,
    const float* __restrict__ delta,
    float* __restrict__ out)
{
    __shared__ __align__(16) short Kb[2][4096];   // 16 KB dbuf (4 x 2KB wave slices)
    __shared__ __align__(16) short Vb[2][4096];   // 16 KB dbuf
    __shared__ float dls[Lsz];                    //  8 KB c2*delta[b][:]
    // total 40 KB

    const int tid  = threadIdx.x;
    const int kq   = tid >> 6;        // wave id == key-quarter
    const int lane = tid & 63;
    const int ln   = lane & 15;
    const int quad = lane >> 4;

    const int bh = blockIdx.x;
    const int b  = bh >> 3, h = bh & 7;
    // spread qt chains so long/short blocks mix across CUs
    const int y = blockIdx.y, g8 = y >> 3, a = y & 7;
    const int qt = (g8 == 0) ? 31 - 2*a : (g8 == 1) ? 2*a
                 : (g8 == 2) ? 30 - 2*a : 2*a + 1;
    const int q0 = qt * 64;
    const int T  = qt + 1;            // 64-key tiles

    const float c2  = 0.125f * 1.44269504f;   // scale * log2(e)
    const float st2 = c2 * tau[b];

    // per-wave incremental staging pointers (tile stride = 4096 shorts = 8 KB)
    const short* gK = Kf + (size_t)bh*(32*4096) + kq*1024 + lane*8;
    const short* gV = Vf + (size_t)bh*(32*4096) + kq*1024 + lane*8;

    // wave's private LDS slices
    short* const myK0 = &Kb[0][kq*1024];
    short* const myV0 = &Vb[0][kq*1024];

    // exactly 4 vmcnt ops per tile - nothing else in the loop touches vmcnt
#define STAGE(buf) do {                                                     \
        short* k_ = (buf) ? myK0 + 4096 : myK0;                             \
        short* v_ = (buf) ? myV0 + 4096 : myV0;                             \
        stage16(gK + 0*512, k_ + 0*512);                                    \
        stage16(gK + 1*512, k_ + 1*512);                                    \
        stage16(gV + 0*512, v_ + 0*512);                                    \
        stage16(gV + 1*512, v_ + 1*512);                                    \
        gK += 4096; gV += 4096;                                             \
        __builtin_amdgcn_sched_barrier(0);                                  \
    } while (0)
#define WAITN(n) do {                                                       \
        asm volatile("s_waitcnt vmcnt(" #n ")" ::: "memory");               \
        __builtin_amdgcn_sched_barrier(0);                                  \
    } while (0)

    STAGE(0);                         // tile 0 in flight first

    // stage c2*delta (256 thr x 8 floats) - prologue only
    {
        const float* dsrc = delta + (size_t)b*Lsz + tid*8;
        float4 av = *(const float4*)(dsrc);
        float4 cv = *(const float4*)(dsrc + 4);
        av.x*=c2; av.y*=c2; av.z*=c2; av.w*=c2;
        cv.x*=c2; cv.y*=c2; cv.z*=c2; cv.w*=c2;
        *(float4*)&dls[tid*8]     = av;
        *(float4*)&dls[tid*8 + 4] = cv;
    }

    // Q fragments in registers (all 64 queries; B-operand of 16x16x32)
    bf16x8 qf[4][2];
    #pragma unroll
    for (int qg = 0; qg < 4; ++qg) {
        const float* qrow = q + (((size_t)b*Lsz + q0 + qg*16 + ln)*Hsz + h)*64;
        float4 a0 = *(const float4*)(qrow + quad*8);
        float4 a1 = *(const float4*)(qrow + quad*8 + 4);
        float4 b0 = *(const float4*)(qrow + 32 + quad*8);
        float4 b1 = *(const float4*)(qrow + 32 + quad*8 + 4);
        qf[qg][0] = (bf16x8){f2bs(a0.x),f2bs(a0.y),f2bs(a0.z),f2bs(a0.w),
                             f2bs(a1.x),f2bs(a1.y),f2bs(a1.z),f2bs(a1.w)};
        qf[qg][1] = (bf16x8){f2bs(b0.x),f2bs(b0.y),f2bs(b0.z),f2bs(b0.w),
                             f2bs(b1.x),f2bs(b1.y),f2bs(b1.z),f2bs(b1.w)};
    }

    f32x4 oacc[4][4];                 // [dg][qg]; O[q=qg*16+ln][d=dg*16+quad*4+i]
    #pragma unroll
    for (int dg = 0; dg < 4; ++dg)
        #pragma unroll
        for (int qg = 0; qg < 4; ++qg)
            oacc[dg][qg] = (f32x4){0.f,0.f,0.f,0.f};
    float l_acc[4] = {0.f,0.f,0.f,0.f};

    __syncthreads();                  // tile 0 + dls resident (single drain)

#define TILE_BODY(t_, MASKED, HASNEXT) do {                                 \
        const short* Kc_ = ((t_) & 1) ? myK0 + 4096 : myK0;                 \
        const short* Vc_ = ((t_) & 1) ? myV0 + 4096 : myV0;                 \
        if (HASNEXT) STAGE(((t_)+1) & 1);                                   \
        if (HASNEXT) WAITN(6); else WAITN(2);      /* K(t) resident */      \
        bf16x8 kf0_ = *(const bf16x8*)(Kc_ + 0*512 + lane*8);               \
        bf16x8 kf1_ = *(const bf16x8*)(Kc_ + 1*512 + lane*8);               \
        f32x4 sacc_[4];                                                     \
        __builtin_amdgcn_s_setprio(1);                                      \
        _Pragma("unroll")                                                   \
        for (int qg = 0; qg < 4; ++qg) {                                    \
            f32x4 z_ = (f32x4){0.f,0.f,0.f,0.f};                            \
            z_ = __builtin_amdgcn_mfma_f32_16x16x32_bf16(kf0_, qf[qg][0], z_, 0,0,0); \
            sacc_[qg] = __builtin_amdgcn_mfma_f32_16x16x32_bf16(kf1_, qf[qg][1], z_, 0,0,0); \
        }                                                                   \
        __builtin_amdgcn_s_setprio(0);                                      \
        if (MASKED) {                                                       \
            _Pragma("unroll")                                               \
            for (int qg = 0; qg < 4; ++qg)                                  \
                _Pragma("unroll")                                           \
                for (int r = 0; r < 4; ++r)                                 \
                    if (kq*16 + quad*4 + r > qg*16 + ln) sacc_[qg][r] = -1e30f; \
        }                                                                   \
        f32x4 dlv_ = *(const f32x4*)&dls[(t_)*64 + kq*16 + quad*4];         \
        bf16x4 pT_[4];                                                      \
        _Pragma("unroll")                                                   \
        for (int qg = 0; qg < 4; ++qg) {                                    \
            float p0_ = __builtin_amdgcn_exp2f(fmaf(sacc_[qg][0], st2, dlv_[0])); \
            float p1_ = __builtin_amdgcn_exp2f(fmaf(sacc_[qg][1], st2, dlv_[1])); \
            float p2_ = __builtin_amdgcn_exp2f(fmaf(sacc_[qg][2], st2, dlv_[2])); \
            float p3_ = __builtin_amdgcn_exp2f(fmaf(sacc_[qg][3], st2, dlv_[3])); \
            l_acc[qg] += (p0_ + p1_) + (p2_ + p3_);                         \
            pT_[qg] = (bf16x4){f2bs_rh(p0_), f2bs_rh(p1_),                  \
                               f2bs_rh(p2_), f2bs_rh(p3_)};                 \
        }                                                                   \
        if (HASNEXT) WAITN(4); else WAITN(0);      /* V(t) resident */      \
        bf16x8 vv0_ = *(const bf16x8*)(Vc_ + 0*512 + lane*8);               \
        bf16x8 vv1_ = *(const bf16x8*)(Vc_ + 1*512 + lane*8);               \
        bf16x4 vf_[4];                                                      \
        vf_[0] = (bf16x4){vv0_[0], vv0_[1], vv0_[2], vv0_[3]};              \
        vf_[1] = (bf16x4){vv0_[4], vv0_[5], vv0_[6], vv0_[7]};              \
        vf_[2] = (bf16x4){vv1_[0], vv1_[1], vv1_[2], vv1_[3]};              \
        vf_[3] = (bf16x4){vv1_[4], vv1_[5], vv1_[6], vv1_[7]};              \
        __builtin_amdgcn_s_setprio(1);                                      \
        _Pragma("unroll")                                                   \
        for (int dg = 0; dg < 4; ++dg)                                      \
            _Pragma("unroll")                                               \
            for (int qg = 0; qg < 4; ++qg)                                  \
                oacc[dg][qg] = __builtin_amdgcn_mfma_f32_16x16x16bf16_1k(   \
                    vf_[dg], pT_[qg], oacc[dg][qg], 0,0,0);                 \
        __builtin_amdgcn_s_setprio(0);                                      \
    } while (0)

    // barrier-free main loop; diagonal (masked) tile last, no staging
    for (int t = 0; t < T - 1; ++t) TILE_BODY(t, false, true);
    TILE_BODY(T - 1, true, false);

    // ---- epilogue: 4-way cross-kq reduction of O and l via LDS overlays ----
    float lq[4];
    #pragma unroll
    for (int qg = 0; qg < 4; ++qg) {
        float s = l_acc[qg];
        s += __shfl_xor(s, 16, 64);
        s += __shfl_xor(s, 32, 64);
        lq[qg] = s;                   // full-wave l for (qg, q=ln), replicated
    }
    float* KbF = (float*)&Kb[0][0];   // 8 KB wave-1 O, layout (dg*4+qg)*256+lane*4
    float* VbF = (float*)&Vb[0][0];   // 8 KB wave-3 O
    float* lred = dls;                // 256 f: [kq][qg][16 q]
    __syncthreads();                  // all loop reads of Kb/Vb/dls done

    if (lane < 16)
        #pragma unroll
        for (int qg = 0; qg < 4; ++qg) lred[kq*64 + qg*16 + ln] = lq[qg];
    if (kq == 1 || kq == 3) {
        float* dst = (kq == 1) ? KbF : VbF;
        #pragma unroll
        for (int dg = 0; dg < 4; ++dg)
            #pragma unroll
            for (int qg = 0; qg < 4; ++qg)
                *(f32x4*)(dst + (dg*4+qg)*256 + lane*4) = oacc[dg][qg];
    }
    __syncthreads();
    if (kq == 0 || kq == 2) {
        const float* srcp = (kq == 0) ? KbF : VbF;
        #pragma unroll
        for (int dg = 0; dg < 4; ++dg)
            #pragma unroll
            for (int qg = 0; qg < 4; ++qg) {
                f32x4 v = *(const f32x4*)(srcp + (dg*4+qg)*256 + lane*4);
                oacc[dg][qg][0] += v[0]; oacc[dg][qg][1] += v[1];
                oacc[dg][qg][2] += v[2]; oacc[dg][qg][3] += v[3];
            }
    }
    __syncthreads();
    if (kq == 2) {
        #pragma unroll
        for (int dg = 0; dg < 4; ++dg)
            #pragma unroll
            for (int qg = 0; qg < 4; ++qg)
                *(f32x4*)(KbF + (dg*4+qg)*256 + lane*4) = oacc[dg][qg];
    }
    __syncthreads();
    if (kq == 0) {
        float inv[4];
        #pragma unroll
        for (int qg = 0; qg < 4; ++qg)
            inv[qg] = 1.0f / (lred[qg*16 + ln] + lred[64 + qg*16 + ln]
                            + lred[128 + qg*16 + ln] + lred[192 + qg*16 + ln]);
        #pragma unroll
        for (int qg = 0; qg < 4; ++qg) {
            float* orow = out + (((size_t)b*Lsz + q0 + qg*16 + ln)*Hsz + h)*64;
            #pragma unroll
            for (int dg = 0; dg < 4; ++dg) {
                f32x4 v = *(const f32x4*)(KbF + (dg*4+qg)*256 + lane*4);
                float4 o = {(oacc[dg][qg][0] + v[0]) * inv[qg],
                            (oacc[dg][qg][1] + v[1]) * inv[qg],
                            (oacc[dg][qg][2] + v[2]) * inv[qg],
                            (oacc[dg][qg][3] + v[3]) * inv[qg]};
                *(float4*)(orow + dg*16 + quad*4) = o;
            }
        }
    }
#undef STAGE
#undef WAITN
#undef TILE_BODY
}

extern "C" void kernel_launch(void* const* d_in, const int* in_sizes, int n_in,
                              void* d_out, int out_size, void* d_ws, size_t ws_size,
                              hipStream_t stream) {
    (void)in_sizes; (void)n_in; (void)out_size; (void)ws_size;
    const float* q     = (const float*)d_in[0];
    const float* k     = (const float*)d_in[1];
    const float* v     = (const float*)d_in[2];
    const float* tau   = (const float*)d_in[3];
    const float* delta = (const float*)d_in[4];
    float* out = (float*)d_out;

    short* Kf = (short*)d_ws;                          // 8 MiB bf16 fragments
    short* Vf = (short*)d_ws + (size_t)(4*1024*1024);  // next 8 MiB

    prep_kv<<<dim3(Bsz*Hsz*32*2), dim3(256), 0, stream>>>(k, v, Kf, Vf);
    dsattn_main<<<dim3(Bsz*Hsz, 32), dim3(256), 0, stream>>>(q, Kf, Vf, tau, delta, out);
}